// Round 1
// baseline (2973.353 us; speedup 1.0000x reference)
//
#include <hip/hip_runtime.h>

// GCN: 2x GCNConv(sym-norm, self-loops) + relu, then linear head.
// Factorization: hs[i] = dinv[i] * (x@W)[i];  agg[d] = sum_{e:dst=d} hs[src_e];
// x_next[d] = relu(dinv[d]*(agg[d] + hs[d]) + b)   (self-loop folded into finalize)

#define FIN 128
#define HIDDEN 64

__global__ __launch_bounds__(256) void k_init_deg(float* deg, int n) {
    int i = blockIdx.x * 256 + threadIdx.x;
    if (i < n) deg[i] = 1.0f;   // self-loop
}

__global__ __launch_bounds__(256) void k_count_deg(const int* __restrict__ dst, float* deg, int e) {
    int i = blockIdx.x * 256 + threadIdx.x;
    if (i < e) atomicAdd(&deg[dst[i]], 1.0f);
}

__global__ __launch_bounds__(256) void k_rsqrt(float* deg, int n) {
    int i = blockIdx.x * 256 + threadIdx.x;
    if (i < n) deg[i] = rsqrtf(deg[i]);
}

// GEMM1: hs[i,:] = dinv[i] * (x[i,:] @ W1)   [N,128]@[128,64]
// Block = 256 thr (4 waves), 16 rows/block. W1 fully in LDS (32KB), x-tile in LDS.
// Lane layout: cg = lane&15 (4 cols), rr = lane>>4 (row within wave's 4 rows).
__global__ __launch_bounds__(256) void k_gemm1(const float4* __restrict__ x4,   // [N,32] f4
                                               const float4* __restrict__ w4,   // [128,16] f4
                                               const float* __restrict__ dinv,
                                               float4* __restrict__ hs4,        // [N,16] f4
                                               int n) {
    __shared__ float4 sW[128 * 16];   // 32 KB
    __shared__ float4 sX[16 * 33];    // pad stride 33 to break bank aliasing
    int tid = threadIdx.x;
    int row0 = blockIdx.x * 16;
#pragma unroll
    for (int i = 0; i < 8; i++) sW[tid + i * 256] = w4[tid + i * 256];
#pragma unroll
    for (int i = 0; i < 2; i++) {
        int idx = tid + i * 256;            // 0..511
        int r = idx >> 5, c = idx & 31;
        if (row0 + r < n) sX[r * 33 + c] = x4[(size_t)(row0 + r) * 32 + c];
    }
    __syncthreads();
    int lane = tid & 63, wave = tid >> 6;
    int cg = lane & 15, rr = lane >> 4;
    int r = wave * 4 + rr;
    float4 acc = make_float4(0.f, 0.f, 0.f, 0.f);
#pragma unroll 8
    for (int kq = 0; kq < 32; kq++) {
        float4 xv = sX[r * 33 + kq];
        float4 w0 = sW[(kq * 4 + 0) * 16 + cg];
        float4 w1 = sW[(kq * 4 + 1) * 16 + cg];
        float4 w2 = sW[(kq * 4 + 2) * 16 + cg];
        float4 w3 = sW[(kq * 4 + 3) * 16 + cg];
        acc.x += xv.x * w0.x + xv.y * w1.x + xv.z * w2.x + xv.w * w3.x;
        acc.y += xv.x * w0.y + xv.y * w1.y + xv.z * w2.y + xv.w * w3.y;
        acc.z += xv.x * w0.z + xv.y * w1.z + xv.z * w2.z + xv.w * w3.z;
        acc.w += xv.x * w0.w + xv.y * w1.w + xv.z * w2.w + xv.w * w3.w;
    }
    int gr = row0 + r;
    if (gr < n) {
        float s = dinv[gr];
        acc.x *= s; acc.y *= s; acc.z *= s; acc.w *= s;
        hs4[(size_t)gr * 16 + cg] = acc;
    }
}

// Edge scatter: agg[dst] += hs[src]. 4 edges per wave: el = lane>>4, cq = lane&15.
__global__ __launch_bounds__(256) void k_edge_agg(const int* __restrict__ src,
                                                  const int* __restrict__ dst,
                                                  const float4* __restrict__ hs4,
                                                  float* __restrict__ agg, int ne) {
    int wid = (blockIdx.x * 256 + threadIdx.x) >> 6;
    int lane = threadIdx.x & 63;
    int el = lane >> 4, cq = lane & 15;
    int e = wid * 4 + el;
    if (e < ne) {
        int s = src[e], d = dst[e];
        float4 v = hs4[(size_t)s * 16 + cq];
        float* a = agg + (size_t)d * 64 + cq * 4;
        atomicAdd(a + 0, v.x);
        atomicAdd(a + 1, v.y);
        atomicAdd(a + 2, v.z);
        atomicAdd(a + 3, v.w);
    }
}

// Finalize layer1 + GEMM2 fused: v = relu(dinv*(agg+hs1)+b1); hs2 = dinv * (v @ W2)
__global__ __launch_bounds__(256) void k_fin1_gemm2(const float4* __restrict__ agg4,
                                                    const float4* __restrict__ hs4,
                                                    const float* __restrict__ dinv,
                                                    const float4* __restrict__ b1_4,  // [16] f4
                                                    const float4* __restrict__ w2_4,  // [64,16] f4
                                                    float4* __restrict__ hs2_4,
                                                    int n) {
    __shared__ float4 sW[64 * 16];    // 16 KB
    __shared__ float4 sV[16 * 17];
    int tid = threadIdx.x;
    int row0 = blockIdx.x * 16;
#pragma unroll
    for (int i = 0; i < 4; i++) sW[tid + i * 256] = w2_4[tid + i * 256];
    {
        int r = tid >> 4, cq = tid & 15;
        int gr = row0 + r;
        if (gr < n) {
            float4 a = agg4[(size_t)gr * 16 + cq];
            float4 h = hs4[(size_t)gr * 16 + cq];
            float4 b = b1_4[cq];
            float s = dinv[gr];
            float4 v;
            v.x = fmaxf(s * (a.x + h.x) + b.x, 0.f);
            v.y = fmaxf(s * (a.y + h.y) + b.y, 0.f);
            v.z = fmaxf(s * (a.z + h.z) + b.z, 0.f);
            v.w = fmaxf(s * (a.w + h.w) + b.w, 0.f);
            sV[r * 17 + cq] = v;
        }
    }
    __syncthreads();
    int lane = tid & 63, wave = tid >> 6;
    int cg = lane & 15, rr = lane >> 4;
    int r = wave * 4 + rr;
    float4 acc = make_float4(0.f, 0.f, 0.f, 0.f);
#pragma unroll 8
    for (int kq = 0; kq < 16; kq++) {
        float4 xv = sV[r * 17 + kq];
        float4 w0 = sW[(kq * 4 + 0) * 16 + cg];
        float4 w1 = sW[(kq * 4 + 1) * 16 + cg];
        float4 w2 = sW[(kq * 4 + 2) * 16 + cg];
        float4 w3 = sW[(kq * 4 + 3) * 16 + cg];
        acc.x += xv.x * w0.x + xv.y * w1.x + xv.z * w2.x + xv.w * w3.x;
        acc.y += xv.x * w0.y + xv.y * w1.y + xv.z * w2.y + xv.w * w3.y;
        acc.z += xv.x * w0.z + xv.y * w1.z + xv.z * w2.z + xv.w * w3.z;
        acc.w += xv.x * w0.w + xv.y * w1.w + xv.z * w2.w + xv.w * w3.w;
    }
    int gr = row0 + r;
    if (gr < n) {
        float s = dinv[gr];
        acc.x *= s; acc.y *= s; acc.z *= s; acc.w *= s;
        hs2_4[(size_t)gr * 16 + cg] = acc;
    }
}

// Head: out[i] = relu(dinv*(agg2+hs2)+b2) @ Wc + bc.  One wave per node.
__global__ __launch_bounds__(256) void k_final(const float* __restrict__ agg,
                                               const float* __restrict__ hs2,
                                               const float* __restrict__ dinv,
                                               const float* __restrict__ b2,
                                               const float* __restrict__ wc,
                                               const float* __restrict__ bc,
                                               float* __restrict__ out, int n) {
    int wid = (blockIdx.x * 256 + threadIdx.x) >> 6;
    int lane = threadIdx.x & 63;
    if (wid >= n) return;
    size_t idx = (size_t)wid * 64 + lane;
    float t = fmaxf(dinv[wid] * (agg[idx] + hs2[idx]) + b2[lane], 0.f) * wc[lane];
#pragma unroll
    for (int off = 32; off > 0; off >>= 1) t += __shfl_down(t, off);
    if (lane == 0) out[wid] = t + bc[0];
}

extern "C" void kernel_launch(void* const* d_in, const int* in_sizes, int n_in,
                              void* d_out, int out_size, void* d_ws, size_t ws_size,
                              hipStream_t stream) {
    const float* x  = (const float*)d_in[0];
    const int*   ei = (const int*)d_in[1];
    const float* W1 = (const float*)d_in[2];
    const float* b1 = (const float*)d_in[3];
    const float* W2 = (const float*)d_in[4];
    const float* b2 = (const float*)d_in[5];
    const float* Wc = (const float*)d_in[6];
    const float* bc = (const float*)d_in[7];
    int n = in_sizes[0] / FIN;      // 100000
    int e = in_sizes[1] / 2;        // 1600000
    const int* srcv = ei;
    const int* dstv = ei + e;

    const size_t SZ = (size_t)n * HIDDEN * sizeof(float);   // 25.6 MB
    char* ws = (char*)d_ws;
    float* dinv = (float*)ws;                     // n floats
    float* hs1  = (float*)(ws + 401408);
    float* agg  = (float*)(ws + 401408 + SZ);
    float* hs2  = (float*)(ws + 401408 + 2 * SZ);

    int nb_n = (n + 255) / 256;
    int nb_e = (e + 255) / 256;
    int nb_rows = (n + 15) / 16;       // 6250
    int nb_edge = (e + 15) / 16;       // 100000 (16 edges/block)
    int nb_fin = (n + 3) / 4;          // 25000 (4 waves/block, wave per node)

    hipMemsetAsync(agg, 0, SZ, stream);
    k_init_deg<<<nb_n, 256, 0, stream>>>(dinv, n);
    k_count_deg<<<nb_e, 256, 0, stream>>>(dstv, dinv, e);
    k_rsqrt<<<nb_n, 256, 0, stream>>>(dinv, n);

    k_gemm1<<<nb_rows, 256, 0, stream>>>((const float4*)x, (const float4*)W1, dinv,
                                         (float4*)hs1, n);
    k_edge_agg<<<nb_edge, 256, 0, stream>>>(srcv, dstv, (const float4*)hs1, agg, e);
    k_fin1_gemm2<<<nb_rows, 256, 0, stream>>>((const float4*)agg, (const float4*)hs1, dinv,
                                              (const float4*)b1, (const float4*)W2,
                                              (float4*)hs2, n);
    hipMemsetAsync(agg, 0, SZ, stream);
    k_edge_agg<<<nb_edge, 256, 0, stream>>>(srcv, dstv, (const float4*)hs2, agg, e);
    k_final<<<nb_fin, 256, 0, stream>>>(agg, hs2, dinv, b2, Wc, bc, (float*)d_out, n);
}

// Round 2
// 480.104 us; speedup vs baseline: 6.1931x; 6.1931x over previous
//
#include <hip/hip_runtime.h>

// GCN: 2x GCNConv(sym-norm, self-loops) + relu, then linear head.
// hs[i] = dinv[i] * (x@W)[i];  agg[d] = sum_{e:dst=d} hs[src_e]  (CSR gather, no atomics);
// x_next[d] = relu(dinv[d]*(agg[d] + hs[d]) + b)   (self-loop folded into finalize)

#define FIN 128
#define HIDDEN 64

// ---------------- CSR build ----------------

__global__ __launch_bounds__(256) void k_count_deg(const int* __restrict__ dst,
                                                   int* __restrict__ deg, int e) {
    int i = blockIdx.x * 256 + threadIdx.x;
    if (i < e) atomicAdd(&deg[dst[i]], 1);
}

// scan level 1: 1024 elems/block (256 thr x 4). Writes exclusive prefix into out,
// per-block totals into blockSums.
__global__ __launch_bounds__(256) void k_scan1(const int* __restrict__ deg,
                                               int* __restrict__ out,
                                               int* __restrict__ blockSums, int n) {
    __shared__ int s[256];
    int tid = threadIdx.x;
    int base = blockIdx.x * 1024 + tid * 4;
    int v0 = (base + 0 < n) ? deg[base + 0] : 0;
    int v1 = (base + 1 < n) ? deg[base + 1] : 0;
    int v2 = (base + 2 < n) ? deg[base + 2] : 0;
    int v3 = (base + 3 < n) ? deg[base + 3] : 0;
    int t1 = v0 + v1, t2 = t1 + v2, t3 = t2 + v3;
    s[tid] = t3;
    __syncthreads();
    for (int off = 1; off < 256; off <<= 1) {
        int x = 0;
        if (tid >= off) x = s[tid - off];
        __syncthreads();
        if (tid >= off) s[tid] += x;
        __syncthreads();
    }
    int excl = s[tid] - t3;   // exclusive prefix before this thread's chunk
    if (base + 0 < n) out[base + 0] = excl;
    if (base + 1 < n) out[base + 1] = excl + v0;
    if (base + 2 < n) out[base + 2] = excl + t1;
    if (base + 3 < n) out[base + 3] = excl + t2;
    if (tid == 255) blockSums[blockIdx.x] = s[255];
}

// scan level 2: single block, exclusive scan of nb (<128) block sums in-place.
__global__ __launch_bounds__(128) void k_scan2(int* __restrict__ blockSums, int nb) {
    __shared__ int s[128];
    int tid = threadIdx.x;
    int v = (tid < nb) ? blockSums[tid] : 0;
    s[tid] = v;
    __syncthreads();
    for (int off = 1; off < 128; off <<= 1) {
        int x = 0;
        if (tid >= off) x = s[tid - off];
        __syncthreads();
        if (tid >= off) s[tid] += x;
        __syncthreads();
    }
    if (tid < nb) blockSums[tid] = s[tid] - v;   // exclusive
}

// scan level 3: add block offsets; also set row_ptr[n] = e.
__global__ __launch_bounds__(256) void k_scan3(int* __restrict__ row_ptr,
                                               const int* __restrict__ blockSums,
                                               int n, int e) {
    int i = blockIdx.x * 256 + threadIdx.x;
    if (i < n) row_ptr[i] += blockSums[i >> 10];
    if (i == 0) row_ptr[n] = e;
}

__global__ __launch_bounds__(256) void k_dinv(const int* __restrict__ deg,
                                              float* __restrict__ dinv, int n) {
    int i = blockIdx.x * 256 + threadIdx.x;
    if (i < n) dinv[i] = rsqrtf((float)deg[i] + 1.0f);   // +1 self-loop
}

__global__ __launch_bounds__(256) void k_scatter(const int* __restrict__ src,
                                                 const int* __restrict__ dst,
                                                 const int* __restrict__ row_ptr,
                                                 int* __restrict__ cursor,
                                                 int* __restrict__ csr_src, int e) {
    int i = blockIdx.x * 256 + threadIdx.x;
    if (i < e) {
        int d = dst[i];
        int pos = row_ptr[d] + atomicAdd(&cursor[d], 1);
        csr_src[pos] = src[i];
    }
}

// ---------------- dense compute ----------------

// GEMM1: hs[i,:] = dinv[i] * (x[i,:] @ W1)   [N,128]@[128,64]
__global__ __launch_bounds__(256) void k_gemm1(const float4* __restrict__ x4,   // [N,32] f4
                                               const float4* __restrict__ w4,   // [128,16] f4
                                               const float* __restrict__ dinv,
                                               float4* __restrict__ hs4,        // [N,16] f4
                                               int n) {
    __shared__ float4 sW[128 * 16];   // 32 KB
    __shared__ float4 sX[16 * 33];
    int tid = threadIdx.x;
    int row0 = blockIdx.x * 16;
#pragma unroll
    for (int i = 0; i < 8; i++) sW[tid + i * 256] = w4[tid + i * 256];
#pragma unroll
    for (int i = 0; i < 2; i++) {
        int idx = tid + i * 256;
        int r = idx >> 5, c = idx & 31;
        if (row0 + r < n) sX[r * 33 + c] = x4[(size_t)(row0 + r) * 32 + c];
    }
    __syncthreads();
    int lane = tid & 63, wave = tid >> 6;
    int cg = lane & 15, rr = lane >> 4;
    int r = wave * 4 + rr;
    float4 acc = make_float4(0.f, 0.f, 0.f, 0.f);
#pragma unroll 8
    for (int kq = 0; kq < 32; kq++) {
        float4 xv = sX[r * 33 + kq];
        float4 w0 = sW[(kq * 4 + 0) * 16 + cg];
        float4 w1 = sW[(kq * 4 + 1) * 16 + cg];
        float4 w2 = sW[(kq * 4 + 2) * 16 + cg];
        float4 w3 = sW[(kq * 4 + 3) * 16 + cg];
        acc.x += xv.x * w0.x + xv.y * w1.x + xv.z * w2.x + xv.w * w3.x;
        acc.y += xv.x * w0.y + xv.y * w1.y + xv.z * w2.y + xv.w * w3.y;
        acc.z += xv.x * w0.z + xv.y * w1.z + xv.z * w2.z + xv.w * w3.z;
        acc.w += xv.x * w0.w + xv.y * w1.w + xv.z * w2.w + xv.w * w3.w;
    }
    int gr = row0 + r;
    if (gr < n) {
        float s = dinv[gr];
        acc.x *= s; acc.y *= s; acc.z *= s; acc.w *= s;
        hs4[(size_t)gr * 16 + cg] = acc;
    }
}

// CSR aggregation: one wave per dst row. 16 lanes/edge (cq), 4 edges in flight (el).
__global__ __launch_bounds__(256) void k_agg_csr(const int* __restrict__ row_ptr,
                                                 const int* __restrict__ csr_src,
                                                 const float4* __restrict__ hs4,
                                                 float4* __restrict__ agg4, int n) {
    int wid = (blockIdx.x * 256 + threadIdx.x) >> 6;
    int lane = threadIdx.x & 63;
    if (wid >= n) return;
    int el = lane >> 4, cq = lane & 15;
    int start = row_ptr[wid], end = row_ptr[wid + 1];
    float4 acc = make_float4(0.f, 0.f, 0.f, 0.f);
    for (int e = start + el; e < end; e += 4) {
        int s = csr_src[e];
        float4 v = hs4[(size_t)s * 16 + cq];
        acc.x += v.x; acc.y += v.y; acc.z += v.z; acc.w += v.w;
    }
    // reduce across the 4 el-groups (lane ^= 16, lane ^= 32)
    acc.x += __shfl_xor(acc.x, 16); acc.y += __shfl_xor(acc.y, 16);
    acc.z += __shfl_xor(acc.z, 16); acc.w += __shfl_xor(acc.w, 16);
    acc.x += __shfl_xor(acc.x, 32); acc.y += __shfl_xor(acc.y, 32);
    acc.z += __shfl_xor(acc.z, 32); acc.w += __shfl_xor(acc.w, 32);
    if (el == 0) agg4[(size_t)wid * 16 + cq] = acc;
}

// Finalize layer1 + GEMM2 fused: v = relu(dinv*(agg+hs1)+b1); hs2 = dinv * (v @ W2)
// NOTE: hs2_4 may alias hs4 — all reads of this block's rows happen before the
// barrier; writes after; no cross-block row sharing.
__global__ __launch_bounds__(256) void k_fin1_gemm2(const float4* __restrict__ agg4,
                                                    const float4* __restrict__ hs4,
                                                    const float* __restrict__ dinv,
                                                    const float4* __restrict__ b1_4,  // [16] f4
                                                    const float4* __restrict__ w2_4,  // [64,16] f4
                                                    float4* __restrict__ hs2_4,
                                                    int n) {
    __shared__ float4 sW[64 * 16];
    __shared__ float4 sV[16 * 17];
    int tid = threadIdx.x;
    int row0 = blockIdx.x * 16;
#pragma unroll
    for (int i = 0; i < 4; i++) sW[tid + i * 256] = w2_4[tid + i * 256];
    {
        int r = tid >> 4, cq = tid & 15;
        int gr = row0 + r;
        if (gr < n) {
            float4 a = agg4[(size_t)gr * 16 + cq];
            float4 h = hs4[(size_t)gr * 16 + cq];
            float4 b = b1_4[cq];
            float s = dinv[gr];
            float4 v;
            v.x = fmaxf(s * (a.x + h.x) + b.x, 0.f);
            v.y = fmaxf(s * (a.y + h.y) + b.y, 0.f);
            v.z = fmaxf(s * (a.z + h.z) + b.z, 0.f);
            v.w = fmaxf(s * (a.w + h.w) + b.w, 0.f);
            sV[r * 17 + cq] = v;
        }
    }
    __syncthreads();
    int lane = tid & 63, wave = tid >> 6;
    int cg = lane & 15, rr = lane >> 4;
    int r = wave * 4 + rr;
    float4 acc = make_float4(0.f, 0.f, 0.f, 0.f);
#pragma unroll 8
    for (int kq = 0; kq < 16; kq++) {
        float4 xv = sV[r * 17 + kq];
        float4 w0 = sW[(kq * 4 + 0) * 16 + cg];
        float4 w1 = sW[(kq * 4 + 1) * 16 + cg];
        float4 w2 = sW[(kq * 4 + 2) * 16 + cg];
        float4 w3 = sW[(kq * 4 + 3) * 16 + cg];
        acc.x += xv.x * w0.x + xv.y * w1.x + xv.z * w2.x + xv.w * w3.x;
        acc.y += xv.x * w0.y + xv.y * w1.y + xv.z * w2.y + xv.w * w3.y;
        acc.z += xv.x * w0.z + xv.y * w1.z + xv.z * w2.z + xv.w * w3.z;
        acc.w += xv.x * w0.w + xv.y * w1.w + xv.z * w2.w + xv.w * w3.w;
    }
    int gr = row0 + r;
    if (gr < n) {
        float s = dinv[gr];
        acc.x *= s; acc.y *= s; acc.z *= s; acc.w *= s;
        hs2_4[(size_t)gr * 16 + cg] = acc;
    }
}

// Head: out[i] = relu(dinv*(agg2+hs2)+b2) @ Wc + bc.  One wave per node.
__global__ __launch_bounds__(256) void k_final(const float* __restrict__ agg,
                                               const float* __restrict__ hs2,
                                               const float* __restrict__ dinv,
                                               const float* __restrict__ b2,
                                               const float* __restrict__ wc,
                                               const float* __restrict__ bc,
                                               float* __restrict__ out, int n) {
    int wid = (blockIdx.x * 256 + threadIdx.x) >> 6;
    int lane = threadIdx.x & 63;
    if (wid >= n) return;
    size_t idx = (size_t)wid * 64 + lane;
    float t = fmaxf(dinv[wid] * (agg[idx] + hs2[idx]) + b2[lane], 0.f) * wc[lane];
#pragma unroll
    for (int off = 32; off > 0; off >>= 1) t += __shfl_down(t, off);
    if (lane == 0) out[wid] = t + bc[0];
}

extern "C" void kernel_launch(void* const* d_in, const int* in_sizes, int n_in,
                              void* d_out, int out_size, void* d_ws, size_t ws_size,
                              hipStream_t stream) {
    const float* x  = (const float*)d_in[0];
    const int*   ei = (const int*)d_in[1];
    const float* W1 = (const float*)d_in[2];
    const float* b1 = (const float*)d_in[3];
    const float* W2 = (const float*)d_in[4];
    const float* b2 = (const float*)d_in[5];
    const float* Wc = (const float*)d_in[6];
    const float* bc = (const float*)d_in[7];
    int n = in_sizes[0] / FIN;      // 100000
    int e = in_sizes[1] / 2;        // 1600000
    const int* srcv = ei;
    const int* dstv = ei + e;

    char* ws = (char*)d_ws;
    const size_t SZ = (size_t)n * HIDDEN * sizeof(float);   // 25.6 MB
    float* dinv    = (float*)(ws + 0);                       // 400 KB
    int*   row_ptr = (int*)(ws + (512u << 10));              // 400 KB @ 512K
    int*   csr_src = (int*)(ws + (1u << 20));                // 6.4 MB @ 1M
    float* hs      = (float*)(ws + (8u << 20));              // 25.6 MB @ 8M (hs1 & hs2 alias)
    float* agg     = (float*)(ws + (8u << 20) + SZ);         // 25.6 MB
    // transient (dead before agg is first written):
    int* deg_i     = (int*)agg;                              // 400 KB
    int* cursor    = (int*)((char*)agg + (512u << 10));      // 400 KB
    int* blockSums = (int*)((char*)agg + (1u << 20));        // small

    int nb_n   = (n + 255) / 256;
    int nb_e   = (e + 255) / 256;
    int nb_sc1 = (n + 1023) / 1024;      // 98
    int nb_rows = (n + 15) / 16;         // 6250
    int nb_wave = (n * 64 + 255) / 256;  // 25000 (one wave per node)

    // CSR build
    hipMemsetAsync(deg_i, 0, (size_t)n * 4, stream);
    hipMemsetAsync(cursor, 0, (size_t)n * 4, stream);
    k_count_deg<<<nb_e, 256, 0, stream>>>(dstv, deg_i, e);
    k_scan1<<<nb_sc1, 256, 0, stream>>>(deg_i, row_ptr, blockSums, n);
    k_scan2<<<1, 128, 0, stream>>>(blockSums, nb_sc1);
    k_scan3<<<nb_n, 256, 0, stream>>>(row_ptr, blockSums, n, e);
    k_dinv<<<nb_n, 256, 0, stream>>>(deg_i, dinv, n);
    k_scatter<<<nb_e, 256, 0, stream>>>(srcv, dstv, row_ptr, cursor, csr_src, e);

    // layer 1
    k_gemm1<<<nb_rows, 256, 0, stream>>>((const float4*)x, (const float4*)W1, dinv,
                                         (float4*)hs, n);
    k_agg_csr<<<nb_wave, 256, 0, stream>>>(row_ptr, csr_src, (const float4*)hs,
                                           (float4*)agg, n);
    k_fin1_gemm2<<<nb_rows, 256, 0, stream>>>((const float4*)agg, (const float4*)hs, dinv,
                                              (const float4*)b1, (const float4*)W2,
                                              (float4*)hs, n);
    // layer 2 + head
    k_agg_csr<<<nb_wave, 256, 0, stream>>>(row_ptr, csr_src, (const float4*)hs,
                                           (float4*)agg, n);
    k_final<<<nb_wave, 256, 0, stream>>>(agg, hs, dinv, b2, Wc, bc, (float*)d_out, n);
}

// Round 3
// 359.105 us; speedup vs baseline: 8.2799x; 1.3369x over previous
//
#include <hip/hip_runtime.h>

// GCN: 2x GCNConv(sym-norm, self-loops) + relu, then linear head.
// hs[i] = dinv[i] * (x@W)[i];  agg[d] = sum_{e:dst=d} hs[src_e]  (CSR gather);
// x_next[d] = relu(dinv[d]*(agg[d] + hs[d]) + b)
// CSR built via two-level bucket sort (dst>>9 buckets, then exact within bucket)
// to keep scatter writes L2-local: WRITE_SIZE ~= payload, no hot global atomics.

#define FIN 128
#define HIDDEN 64
#define NBUCK 196          // ceil(100000/512)
#define EPB 8192           // edges per block in bucket kernels

// ---- A1: global bucket histogram (dst>>9) ----
__global__ __launch_bounds__(256) void k_hist_bucket(const int* __restrict__ dst,
                                                     int* __restrict__ bhist, int e) {
    __shared__ int h[NBUCK];
    int tid = threadIdx.x;
    if (tid < NBUCK) h[tid] = 0;
    __syncthreads();
    int start = blockIdx.x * EPB;
#pragma unroll
    for (int i = 0; i < EPB / 256; i++) {
        int idx = start + tid + i * 256;
        if (idx < e) atomicAdd(&h[dst[idx] >> 9], 1);
    }
    __syncthreads();
    if (tid < NBUCK && h[tid] > 0) atomicAdd(&bhist[tid], h[tid]);
}

// ---- A2: scan 196 bucket counts -> bases + cursors; row_ptr[n]=e ----
__global__ __launch_bounds__(256) void k_scan_bucket(const int* __restrict__ bhist,
                                                     int* __restrict__ bbase,
                                                     int* __restrict__ bcursor,
                                                     int* __restrict__ row_ptr,
                                                     int n, int e) {
    __shared__ int s[256];
    int tid = threadIdx.x;
    int v = (tid < NBUCK) ? bhist[tid] : 0;
    s[tid] = v;
    __syncthreads();
    for (int off = 1; off < 256; off <<= 1) {
        int x = 0;
        if (tid >= off) x = s[tid - off];
        __syncthreads();
        if (tid >= off) s[tid] += x;
        __syncthreads();
    }
    int excl = s[tid] - v;
    if (tid <= NBUCK) bbase[tid] = excl;          // bbase[NBUCK] = total = e
    if (tid < NBUCK) bcursor[tid] = excl;
    if (tid == 0) row_ptr[n] = e;
}

// ---- A3: scatter (src,dst) pairs into bucket regions, per-block reservations ----
__global__ __launch_bounds__(256) void k_scatter_bucket(const int* __restrict__ src,
                                                        const int* __restrict__ dst,
                                                        int* __restrict__ bcursor,
                                                        int2* __restrict__ pairs, int e) {
    __shared__ int h[NBUCK], base_s[NBUCK], cur[NBUCK];
    int tid = threadIdx.x;
    if (tid < NBUCK) { h[tid] = 0; cur[tid] = 0; }
    __syncthreads();
    int start = blockIdx.x * EPB;
#pragma unroll
    for (int i = 0; i < EPB / 256; i++) {
        int idx = start + tid + i * 256;
        if (idx < e) atomicAdd(&h[dst[idx] >> 9], 1);
    }
    __syncthreads();
    if (tid < NBUCK && h[tid] > 0) base_s[tid] = atomicAdd(&bcursor[tid], h[tid]);
    __syncthreads();
#pragma unroll
    for (int i = 0; i < EPB / 256; i++) {
        int idx = start + tid + i * 256;
        if (idx < e) {
            int d = dst[idx];
            int b = d >> 9;
            int pos = base_s[b] + atomicAdd(&cur[b], 1);
            pairs[pos] = make_int2(src[idx], d);
        }
    }
}

// ---- B: per-bucket exact CSR + row_ptr + dinv (512 nodes/bucket) ----
__global__ __launch_bounds__(256) void k_csr_bucket(const int2* __restrict__ pairs,
                                                    const int* __restrict__ bbase,
                                                    int* __restrict__ row_ptr,
                                                    float* __restrict__ dinv,
                                                    int* __restrict__ csr_src, int n) {
    __shared__ int cnt[512];
    __shared__ int off[512];
    __shared__ int ws2[256];
    int tid = threadIdx.x;
    int b = blockIdx.x;
    int node0 = b << 9;
    cnt[tid] = 0; cnt[tid + 256] = 0;
    __syncthreads();
    int s0 = bbase[b], s1 = bbase[b + 1];
    for (int i = s0 + tid; i < s1; i += 256) atomicAdd(&cnt[pairs[i].y & 511], 1);
    __syncthreads();
    int c0 = cnt[2 * tid], c1 = cnt[2 * tid + 1];
    int tsum = c0 + c1;
    ws2[tid] = tsum;
    __syncthreads();
    for (int o = 1; o < 256; o <<= 1) {
        int x = 0;
        if (tid >= o) x = ws2[tid - o];
        __syncthreads();
        if (tid >= o) ws2[tid] += x;
        __syncthreads();
    }
    int excl = ws2[tid] - tsum;
    off[2 * tid] = excl;
    off[2 * tid + 1] = excl + c0;
    int n0 = node0 + 2 * tid, n1 = node0 + 2 * tid + 1;
    if (n0 < n) { row_ptr[n0] = s0 + excl;      dinv[n0] = rsqrtf((float)c0 + 1.0f); }
    if (n1 < n) { row_ptr[n1] = s0 + excl + c0; dinv[n1] = rsqrtf((float)c1 + 1.0f); }
    cnt[2 * tid] = 0; cnt[2 * tid + 1] = 0;
    __syncthreads();
    for (int i = s0 + tid; i < s1; i += 256) {
        int2 p = pairs[i];
        int l = p.y & 511;
        int pos = s0 + off[l] + atomicAdd(&cnt[l], 1);
        csr_src[pos] = p.x;
    }
}

// ---------------- dense compute ----------------

// GEMM1: hs[i,:] = dinv[i] * (x[i,:] @ W1)   [N,128]@[128,64]
__global__ __launch_bounds__(256) void k_gemm1(const float4* __restrict__ x4,   // [N,32] f4
                                               const float4* __restrict__ w4,   // [128,16] f4
                                               const float* __restrict__ dinv,
                                               float4* __restrict__ hs4,        // [N,16] f4
                                               int n) {
    __shared__ float4 sW[128 * 16];   // 32 KB
    __shared__ float4 sX[16 * 33];
    int tid = threadIdx.x;
    int row0 = blockIdx.x * 16;
#pragma unroll
    for (int i = 0; i < 8; i++) sW[tid + i * 256] = w4[tid + i * 256];
#pragma unroll
    for (int i = 0; i < 2; i++) {
        int idx = tid + i * 256;
        int r = idx >> 5, c = idx & 31;
        if (row0 + r < n) sX[r * 33 + c] = x4[(size_t)(row0 + r) * 32 + c];
    }
    __syncthreads();
    int lane = tid & 63, wave = tid >> 6;
    int cg = lane & 15, rr = lane >> 4;
    int r = wave * 4 + rr;
    float4 acc = make_float4(0.f, 0.f, 0.f, 0.f);
#pragma unroll 8
    for (int kq = 0; kq < 32; kq++) {
        float4 xv = sX[r * 33 + kq];
        float4 w0 = sW[(kq * 4 + 0) * 16 + cg];
        float4 w1 = sW[(kq * 4 + 1) * 16 + cg];
        float4 w2 = sW[(kq * 4 + 2) * 16 + cg];
        float4 w3 = sW[(kq * 4 + 3) * 16 + cg];
        acc.x += xv.x * w0.x + xv.y * w1.x + xv.z * w2.x + xv.w * w3.x;
        acc.y += xv.x * w0.y + xv.y * w1.y + xv.z * w2.y + xv.w * w3.y;
        acc.z += xv.x * w0.z + xv.y * w1.z + xv.z * w2.z + xv.w * w3.z;
        acc.w += xv.x * w0.w + xv.y * w1.w + xv.z * w2.w + xv.w * w3.w;
    }
    int gr = row0 + r;
    if (gr < n) {
        float s = dinv[gr];
        acc.x *= s; acc.y *= s; acc.z *= s; acc.w *= s;
        hs4[(size_t)gr * 16 + cg] = acc;
    }
}

// CSR aggregation: one wave per dst row. 16 lanes/edge (cq), 4 edges in flight (el).
__global__ __launch_bounds__(256) void k_agg_csr(const int* __restrict__ row_ptr,
                                                 const int* __restrict__ csr_src,
                                                 const float4* __restrict__ hs4,
                                                 float4* __restrict__ agg4, int n) {
    int wid = (blockIdx.x * 256 + threadIdx.x) >> 6;
    int lane = threadIdx.x & 63;
    if (wid >= n) return;
    int el = lane >> 4, cq = lane & 15;
    int start = row_ptr[wid], end = row_ptr[wid + 1];
    float4 acc = make_float4(0.f, 0.f, 0.f, 0.f);
    for (int e = start + el; e < end; e += 4) {
        int s = csr_src[e];
        float4 v = hs4[(size_t)s * 16 + cq];
        acc.x += v.x; acc.y += v.y; acc.z += v.z; acc.w += v.w;
    }
    acc.x += __shfl_xor(acc.x, 16); acc.y += __shfl_xor(acc.y, 16);
    acc.z += __shfl_xor(acc.z, 16); acc.w += __shfl_xor(acc.w, 16);
    acc.x += __shfl_xor(acc.x, 32); acc.y += __shfl_xor(acc.y, 32);
    acc.z += __shfl_xor(acc.z, 32); acc.w += __shfl_xor(acc.w, 32);
    if (el == 0) agg4[(size_t)wid * 16 + cq] = acc;
}

// Finalize layer1 + GEMM2 fused: v = relu(dinv*(agg+hs1)+b1); hs2 = dinv * (v @ W2)
__global__ __launch_bounds__(256) void k_fin1_gemm2(const float4* __restrict__ agg4,
                                                    const float4* __restrict__ hs4,
                                                    const float* __restrict__ dinv,
                                                    const float4* __restrict__ b1_4,  // [16] f4
                                                    const float4* __restrict__ w2_4,  // [64,16] f4
                                                    float4* __restrict__ hs2_4,
                                                    int n) {
    __shared__ float4 sW[64 * 16];
    __shared__ float4 sV[16 * 17];
    int tid = threadIdx.x;
    int row0 = blockIdx.x * 16;
#pragma unroll
    for (int i = 0; i < 4; i++) sW[tid + i * 256] = w2_4[tid + i * 256];
    {
        int r = tid >> 4, cq = tid & 15;
        int gr = row0 + r;
        if (gr < n) {
            float4 a = agg4[(size_t)gr * 16 + cq];
            float4 h = hs4[(size_t)gr * 16 + cq];
            float4 b = b1_4[cq];
            float s = dinv[gr];
            float4 v;
            v.x = fmaxf(s * (a.x + h.x) + b.x, 0.f);
            v.y = fmaxf(s * (a.y + h.y) + b.y, 0.f);
            v.z = fmaxf(s * (a.z + h.z) + b.z, 0.f);
            v.w = fmaxf(s * (a.w + h.w) + b.w, 0.f);
            sV[r * 17 + cq] = v;
        }
    }
    __syncthreads();
    int lane = tid & 63, wave = tid >> 6;
    int cg = lane & 15, rr = lane >> 4;
    int r = wave * 4 + rr;
    float4 acc = make_float4(0.f, 0.f, 0.f, 0.f);
#pragma unroll 8
    for (int kq = 0; kq < 16; kq++) {
        float4 xv = sV[r * 17 + kq];
        float4 w0 = sW[(kq * 4 + 0) * 16 + cg];
        float4 w1 = sW[(kq * 4 + 1) * 16 + cg];
        float4 w2 = sW[(kq * 4 + 2) * 16 + cg];
        float4 w3 = sW[(kq * 4 + 3) * 16 + cg];
        acc.x += xv.x * w0.x + xv.y * w1.x + xv.z * w2.x + xv.w * w3.x;
        acc.y += xv.x * w0.y + xv.y * w1.y + xv.z * w2.y + xv.w * w3.y;
        acc.z += xv.x * w0.z + xv.y * w1.z + xv.z * w2.z + xv.w * w3.z;
        acc.w += xv.x * w0.w + xv.y * w1.w + xv.z * w2.w + xv.w * w3.w;
    }
    int gr = row0 + r;
    if (gr < n) {
        float s = dinv[gr];
        acc.x *= s; acc.y *= s; acc.z *= s; acc.w *= s;
        hs2_4[(size_t)gr * 16 + cg] = acc;
    }
}

// Head: out[i] = relu(dinv*(agg2+hs2)+b2) @ Wc + bc.  One wave per node.
__global__ __launch_bounds__(256) void k_final(const float* __restrict__ agg,
                                               const float* __restrict__ hs2,
                                               const float* __restrict__ dinv,
                                               const float* __restrict__ b2,
                                               const float* __restrict__ wc,
                                               const float* __restrict__ bc,
                                               float* __restrict__ out, int n) {
    int wid = (blockIdx.x * 256 + threadIdx.x) >> 6;
    int lane = threadIdx.x & 63;
    if (wid >= n) return;
    size_t idx = (size_t)wid * 64 + lane;
    float t = fmaxf(dinv[wid] * (agg[idx] + hs2[idx]) + b2[lane], 0.f) * wc[lane];
#pragma unroll
    for (int off = 32; off > 0; off >>= 1) t += __shfl_down(t, off);
    if (lane == 0) out[wid] = t + bc[0];
}

extern "C" void kernel_launch(void* const* d_in, const int* in_sizes, int n_in,
                              void* d_out, int out_size, void* d_ws, size_t ws_size,
                              hipStream_t stream) {
    const float* x  = (const float*)d_in[0];
    const int*   ei = (const int*)d_in[1];
    const float* W1 = (const float*)d_in[2];
    const float* b1 = (const float*)d_in[3];
    const float* W2 = (const float*)d_in[4];
    const float* b2 = (const float*)d_in[5];
    const float* Wc = (const float*)d_in[6];
    const float* bc = (const float*)d_in[7];
    int n = in_sizes[0] / FIN;      // 100000
    int e = in_sizes[1] / 2;        // 1600000
    const int* srcv = ei;
    const int* dstv = ei + e;

    char* ws = (char*)d_ws;
    const size_t SZ = (size_t)n * HIDDEN * sizeof(float);   // 25.6 MB
    float* dinv    = (float*)(ws + 0);                       // 400 KB
    int*   row_ptr = (int*)(ws + (512u << 10));              // 400 KB
    int*   csr_src = (int*)(ws + (1u << 20));                // 6.4 MB
    float* hs      = (float*)(ws + (8u << 20));              // 25.6 MB (hs1 & hs2 alias)
    float* agg     = (float*)(ws + (8u << 20) + SZ);         // 25.6 MB
    // transients aliased into agg (dead before agg is first written):
    int2* pairs    = (int2*)agg;                             // 12.8 MB
    int*  bhist    = (int*)((char*)agg + (16u << 20));       // 784 B
    int*  bbase    = (int*)((char*)agg + (16u << 20) + 4096);
    int*  bcursor  = (int*)((char*)agg + (16u << 20) + 8192);

    int nb_edge = (e + EPB - 1) / EPB;   // 196
    int nb_rows = (n + 15) / 16;         // 6250
    int nb_wave = (n * 64 + 255) / 256;  // 25000 (one wave per node)

    // CSR build (bucketed, no hot atomics)
    hipMemsetAsync(bhist, 0, NBUCK * sizeof(int), stream);
    k_hist_bucket<<<nb_edge, 256, 0, stream>>>(dstv, bhist, e);
    k_scan_bucket<<<1, 256, 0, stream>>>(bhist, bbase, bcursor, row_ptr, n, e);
    k_scatter_bucket<<<nb_edge, 256, 0, stream>>>(srcv, dstv, bcursor, pairs, e);
    k_csr_bucket<<<NBUCK, 256, 0, stream>>>(pairs, bbase, row_ptr, dinv, csr_src, n);

    // layer 1
    k_gemm1<<<nb_rows, 256, 0, stream>>>((const float4*)x, (const float4*)W1, dinv,
                                         (float4*)hs, n);
    k_agg_csr<<<nb_wave, 256, 0, stream>>>(row_ptr, csr_src, (const float4*)hs,
                                           (float4*)agg, n);
    k_fin1_gemm2<<<nb_rows, 256, 0, stream>>>((const float4*)agg, (const float4*)hs, dinv,
                                              (const float4*)b1, (const float4*)W2,
                                              (float4*)hs, n);
    // layer 2 + head
    k_agg_csr<<<nb_wave, 256, 0, stream>>>(row_ptr, csr_src, (const float4*)hs,
                                           (float4*)agg, n);
    k_final<<<nb_wave, 256, 0, stream>>>(agg, hs, dinv, b2, Wc, bc, (float*)d_out, n);
}